// Round 9
// baseline (259.082 us; speedup 1.0000x reference)
//
#include <hip/hip_runtime.h>
#include <hip/hip_bf16.h>
#include <math.h>

#define B_ 16
#define N_ 256
#define D_ 128
#define H_ 8
#define HD_ 16
#define EPS_ 1e-8f
#define PI_F 3.14159265358979323846f
#define TWO_PI_F 6.28318530717958647692f
#define INV_TWO_PI_F 0.15915494309189533577f
#define L2E_F 1.4426950408889634f

// ---------------- workspace layout (float units) ----------------
#define OFF_PT   0               // 4096
#define OFF_RAP  4096
#define OFF_PHI  8192
#define OFF_PX   12288
#define OFF_PY   16384
#define OFF_PZ   20480
#define OFF_E    24576
#define OFF_Q    28672           // f16 region: QH/KH/KL/VH head-major, each 524288 f16
#define OFF_BIAS (28672 + 3*524288)     // 8388608 floats (B,H,N,N), upper-tri tiles only
#define OFF_AO   (OFF_BIAS + 8388608)   // 524288
#define OFF_WPACK (OFF_AO + 524288)     // packed f16 weight frags

// packed weight-frag offsets (f16 units, relative to wp)
#define UA0  0        // 2048 : layer0 combined hi/lo k-slot packing
#define UA1H 2048     // 4096
#define UA1L 6144     // 4096
#define UA2H 10240    // 4096
#define UA2L 14336    // 4096
#define UA3H 18432    // 1024
#define UA3L 19456    // 1024
#define UQKV 20480    // 4 matrices (wq,wk,wv,wo): each hi 16384 + lo 16384

typedef _Float16 f16x8 __attribute__((ext_vector_type(8)));
typedef _Float16 f16x4 __attribute__((ext_vector_type(4)));
typedef _Float16 f16x2 __attribute__((ext_vector_type(2)));
typedef __attribute__((ext_vector_type(4))) float f4;
typedef __attribute__((ext_vector_type(4))) unsigned int u4;

__device__ __forceinline__ unsigned pkh2(float a, float b) {
    f16x2 v = { (_Float16)a, (_Float16)b };          // RNE conversions
    return __builtin_bit_cast(unsigned, v);
}
__device__ __forceinline__ float f16res(float x) {   // exact residual of RNE f16
    return x - (float)(_Float16)x;
}

__device__ __forceinline__ float gelu_f(float x) {
    // tanh-approx gelu == x * sigmoid(y); y*log2e = 2.3022079x + 0.10294337x^3
    float y2 = x * fmaf(0.10294337f, x * x, 2.3022079f);
    float e = __builtin_amdgcn_exp2f(-y2);           // inf-safe both tails
    return x * __builtin_amdgcn_rcpf(1.0f + e);
}

// kappa permutation: k-slot (ks,q,j) <-> original index (2*(j>>2)+ks)*16 + q*4 + (j&3)

// ---------------- K_A: weight packing (blocks 0-63) + particle features (64-79) -------------
__global__ __launch_bounds__(256) void k_prep(
    const float* __restrict__ w0, const float* __restrict__ w1,
    const float* __restrict__ w2, const float* __restrict__ w3,
    const float* __restrict__ wq, const float* __restrict__ wk,
    const float* __restrict__ wv, const float* __restrict__ wo,
    const float* __restrict__ x_pf,
    _Float16* __restrict__ wp, float* __restrict__ ws) {
    if (blockIdx.x >= 64) {
        int idx = (blockIdx.x - 64) * 256 + threadIdx.x;   // 0..4095
        int b = idx >> 8, n = idx & 255;
        const float* base = x_pf + (size_t)b * 4 * N_;
        float px = base[0 * N_ + n];
        float py = base[1 * N_ + n];
        float pz = base[2 * N_ + n];
        float e  = base[3 * N_ + n];
        float pt  = sqrtf(fmaxf(px * px + py * py, EPS_));
        float rap = 0.5f * log1pf(2.0f * pz / fmaxf(e - pz, 1e-20f));
        float phi = atan2f(py, px);
        ws[OFF_PT  + idx] = pt;
        ws[OFF_RAP + idx] = rap;
        ws[OFF_PHI + idx] = phi;
        ws[OFF_PX  + idx] = px;
        ws[OFF_PY  + idx] = py;
        ws[OFF_PZ  + idx] = pz;
        ws[OFF_E   + idx] = e;
        return;
    }
    int id0 = blockIdx.x * 256 + threadIdx.x;
    const int gs = 64 * 256;
    for (int e = id0; e < 2048; e += gs) {
        int fi = e >> 3, j = e & 7;
        int mt = fi >> 6, lane = fi & 63;
        int q = lane >> 4, ln = lane & 15;
        int m = mt * 16 + ln;
        _Float16 v = (_Float16)0.0f;
        if (q == 0) v = (j < 4) ? (_Float16)w0[j * 64 + m]
                                : (_Float16)f16res(w0[(j - 4) * 64 + m]);
        else if (q == 1) v = (j < 4) ? (_Float16)w0[j * 64 + m] : (_Float16)0.0f;
        wp[UA0 + e] = v;
    }
    for (int e = id0; e < 4096; e += gs) {
        int fi = e >> 3, j = e & 7;
        int mt = fi >> 7, ks = (fi >> 6) & 1, lane = fi & 63;
        int q = lane >> 4;
        int m = mt * 16 + (lane & 15);
        int k = (2 * (j >> 2) + ks) * 16 + q * 4 + (j & 3);   // kappa
        float x1 = w1[k * 64 + m];
        wp[UA1H + e] = (_Float16)x1;
        wp[UA1L + e] = (_Float16)f16res(x1);
        float x2 = w2[k * 64 + m];
        wp[UA2H + e] = (_Float16)x2;
        wp[UA2L + e] = (_Float16)f16res(x2);
    }
    for (int e = id0; e < 1024; e += gs) {
        int fi = e >> 3, j = e & 7;
        int ks = fi >> 6, lane = fi & 63;
        int q = lane >> 4;
        int m = lane & 15;
        int k = (2 * (j >> 2) + ks) * 16 + q * 4 + (j & 3);   // kappa
        float x = (m < 8) ? w3[k * 8 + m] : 0.0f;
        wp[UA3H + e] = (_Float16)x;
        wp[UA3L + e] = (_Float16)f16res(x);
    }
    const float* mats[4] = { wq, wk, wv, wo };
#pragma unroll 1
    for (int mi = 0; mi < 4; ++mi) {
        const float* W = mats[mi];
        _Float16* dst = wp + UQKV + mi * 32768;
        for (int e = id0; e < 16384; e += gs) {
            int fi = e >> 3, j = e & 7;
            int mt = fi >> 8, ks = (fi >> 6) & 3, lane = fi & 63;
            int k = ks * 32 + ((lane >> 4) << 3) + j;
            int o = mt * 16 + (lane & 15);
            float x = W[k * 128 + o];
            dst[e] = (_Float16)x;
            dst[16384 + e] = (_Float16)f16res(x);
        }
    }
}

// epilogue: bias + gelu on C-layout accs, pack straight into next-layer B-frags (in-lane).
__device__ __forceinline__ void epi_frag(const f4 (&acc)[4][4], const float* __restrict__ bg,
                                         int q, u4 (&Bu)[4][2]) {
#pragma unroll
    for (int mt = 0; mt < 4; ++mt) {
        f4 bv = *(const f4*)&bg[mt * 16 + q * 4];
        int ks = mt & 1, hi = (mt >> 1) * 2;
#pragma unroll
        for (int nt = 0; nt < 4; ++nt) {
            float g0 = gelu_f(acc[mt][nt][0] + bv[0]);
            float g1 = gelu_f(acc[mt][nt][1] + bv[1]);
            float g2 = gelu_f(acc[mt][nt][2] + bv[2]);
            float g3 = gelu_f(acc[mt][nt][3] + bv[3]);
            Bu[nt][ks][hi]     = pkh2(g0, g1);
            Bu[nt][ks][hi + 1] = pkh2(g2, g3);
        }
    }
}

__device__ __forceinline__ void mid_layer(f4 (&acc)[4][4],
                                          const _Float16* __restrict__ wh,
                                          const _Float16* __restrict__ wl,
                                          int lane, const u4 (&Bu)[4][2]) {
    const f4 zero4 = { 0.f, 0.f, 0.f, 0.f };
#pragma unroll
    for (int mt = 0; mt < 4; ++mt) {
        f16x8 ah0 = *(const f16x8*)&wh[((mt * 2 + 0) * 64 + lane) * 8];
        f16x8 ah1 = *(const f16x8*)&wh[((mt * 2 + 1) * 64 + lane) * 8];
        f16x8 al0 = *(const f16x8*)&wl[((mt * 2 + 0) * 64 + lane) * 8];
        f16x8 al1 = *(const f16x8*)&wl[((mt * 2 + 1) * 64 + lane) * 8];
#pragma unroll
        for (int nt = 0; nt < 4; ++nt) {
            f16x8 b0 = __builtin_bit_cast(f16x8, Bu[nt][0]);
            f16x8 b1 = __builtin_bit_cast(f16x8, Bu[nt][1]);
            f4 c = zero4;
            c = __builtin_amdgcn_mfma_f32_16x16x32_f16(ah0, b0, c, 0, 0, 0);
            c = __builtin_amdgcn_mfma_f32_16x16x32_f16(al0, b0, c, 0, 0, 0);
            c = __builtin_amdgcn_mfma_f32_16x16x32_f16(ah1, b1, c, 0, 0, 0);
            c = __builtin_amdgcn_mfma_f32_16x16x32_f16(al1, b1, c, 0, 0, 0);
            acc[mt][nt] = c;
        }
    }
}

// ---------------- split-f16 64-out x 16-token MFMA core ----------------
__device__ __forceinline__ void mfma_core64x16(
    const float* __restrict__ xrow, const _Float16* __restrict__ wpm,
    int mtbase, const float* __restrict__ biasv, int lane, f4 (&cc)[4]) {
    int q = lane >> 4;
    const f4 zero4 = { 0.f, 0.f, 0.f, 0.f };
    f16x8 Bh[4], Bl[4];
#pragma unroll
    for (int ks = 0; ks < 4; ++ks) {
        const float* p = xrow + ks * 32 + q * 8;
        float4 xa = ((const float4*)p)[0];
        float4 xb = ((const float4*)p)[1];
        u4 hu = { pkh2(xa.x, xa.y), pkh2(xa.z, xa.w), pkh2(xb.x, xb.y), pkh2(xb.z, xb.w) };
        u4 lu = { pkh2(f16res(xa.x), f16res(xa.y)), pkh2(f16res(xa.z), f16res(xa.w)),
                  pkh2(f16res(xb.x), f16res(xb.y)), pkh2(f16res(xb.z), f16res(xb.w)) };
        Bh[ks] = __builtin_bit_cast(f16x8, hu);
        Bl[ks] = __builtin_bit_cast(f16x8, lu);
    }
#pragma unroll
    for (int mtl = 0; mtl < 4; ++mtl) {
        int mt = mtbase + mtl;
        f4 c = zero4;
#pragma unroll
        for (int ks = 0; ks < 4; ++ks) {
            const _Float16* fa = wpm + ((size_t)((mt * 4 + ks) * 64 + lane)) * 8;
            f16x8 ah = *(const f16x8*)fa;
            f16x8 al = *(const f16x8*)(fa + 16384);
            c = __builtin_amdgcn_mfma_f32_16x16x32_f16(ah, Bh[ks], c, 0, 0, 0);
            c = __builtin_amdgcn_mfma_f32_16x16x32_f16(ah, Bl[ks], c, 0, 0, 0);
            c = __builtin_amdgcn_mfma_f32_16x16x32_f16(al, Bh[ks], c, 0, 0, 0);
        }
        f4 bv = *(const f4*)&biasv[mtl * 16 + q * 4];
        cc[mtl] = c + bv;
    }
}

// ---------------- K_B: QKV (blocks 0-383) + symmetric pair MLP (blocks 384+) ----------
// Q/K/V outputs stored HEAD-MAJOR: [b][h][tok][16] f16 -> fully coalesced attn loads.
__global__ __launch_bounds__(256, 8) void k_pair_qkv(
    const float* __restrict__ ws, const _Float16* __restrict__ wp,
    const float* __restrict__ b0g, const float* __restrict__ b1g,
    const float* __restrict__ b2g, const float* __restrict__ b3g,
    float* __restrict__ bias_out,
    const float* __restrict__ xf,
    const float* __restrict__ bqv, const float* __restrict__ bkv, const float* __restrict__ bvv,
    _Float16* __restrict__ qh, _Float16* __restrict__ kh,
    _Float16* __restrict__ kl, _Float16* __restrict__ vh) {
    int tid = threadIdx.x;
    int lane = tid & 63;
    int ln = lane & 15, q = lane >> 4;

    if (blockIdx.x < 384) {
        // -------- QKV projection -> head-major packed f16 outputs --------
        int wid = blockIdx.x * 4 + (tid >> 6);       // 0..1535
        int og = wid % 6, tg = wid / 6;
        int mi = og >> 1, ch = og & 1;
        const _Float16* wpm = wp + UQKV + mi * 32768;
        const float* bias = (mi == 0) ? bqv : ((mi == 1) ? bkv : bvv);
        size_t tok = (size_t)(tg * 16 + ln);
        f4 cc[4];
        mfma_core64x16(xf + tok * 128, wpm, ch * 4, bias + ch * 64, lane, cc);
        _Float16* hout = (mi == 0) ? qh : ((mi == 1) ? kh : vh);
        int b = (int)(tok >> 8), tl = (int)(tok & 255);
#pragma unroll
        for (int mtl = 0; mtl < 4; ++mtl) {
            int head = ch * 4 + mtl;
            size_t off = ((size_t)((b * 8 + head) * 256 + tl)) * 16 + q * 4;
            f16x4 hv;
#pragma unroll
            for (int r = 0; r < 4; ++r) hv[r] = (_Float16)cc[mtl][r];
            *(f16x4*)&hout[off] = hv;
            if (mi == 1) {
                f16x4 lv;
#pragma unroll
                for (int r = 0; r < 4; ++r) lv[r] = (_Float16)(cc[mtl][r] - (float)hv[r]);
                *(f16x4*)&kl[off] = lv;
            }
        }
        return;
    }

    // -------- pair MLP (upper-triangle wave-tiles; no mirror writes) --------
    int w2 = (blockIdx.x - 384) * 4 + (tid >> 6);    // 0..10239
    int b = w2 / 640;
    int w = w2 - b * 640;
    int it, rr, nj;
    if (w < 256)      { it = 0; rr = w;       nj = 4; }
    else if (w < 448) { it = 1; rr = w - 256; nj = 3; }
    else if (w < 576) { it = 2; rr = w - 448; nj = 2; }
    else              { it = 3; rr = w - 576; nj = 1; }
    int i  = it * 64 + rr / nj;
    int jt = it + rr % nj;
    int j0 = jt * 64;
    int row = (b << 8) + i;

    unsigned FH01, FH23, FL01, FL23;
    {
        int ib = row;
        int jb = (b << 8) + j0 + lane;
        float pt_i = ws[OFF_PT + ib],  rap_i = ws[OFF_RAP + ib], phi_i = ws[OFF_PHI + ib];
        float px_i = ws[OFF_PX + ib],  py_i  = ws[OFF_PY  + ib];
        float pz_i = ws[OFF_PZ + ib],  e_i   = ws[OFF_E   + ib];
        float pt_j = ws[OFF_PT + jb],  rap_j = ws[OFF_RAP + jb], phi_j = ws[OFF_PHI + jb];
        float px_j = ws[OFF_PX + jb],  py_j  = ws[OFF_PY  + jb];
        float pz_j = ws[OFF_PZ + jb],  e_j   = ws[OFF_E   + jb];

        float drap = rap_i - rap_j;
        float xw = phi_i - phi_j + PI_F;
        float mw = xw - TWO_PI_F * floorf(xw * INV_TWO_PI_F);
        float dphi = mw - PI_F;
        float delta = sqrtf(drap * drap + dphi * dphi);
        float f2 = __logf(fmaxf(delta, EPS_));
        float ptmin = fminf(pt_i, pt_j);
        float f0 = __logf(fmaxf(ptmin * delta, EPS_));
        float f1 = __logf(fmaxf(ptmin / fmaxf(pt_i + pt_j, EPS_), EPS_));
        float es = e_i + e_j, pxs = px_i + px_j, pys = py_i + py_j, pzs = pz_i + pz_j;
        float f3 = __logf(fmaxf(es * es - pxs * pxs - pys * pys - pzs * pzs, EPS_));

        FH01 = pkh2(f0, f1);
        FH23 = pkh2(f2, f3);
        FL01 = pkh2(f16res(f0), f16res(f1));
        FL23 = pkh2(f16res(f2), f16res(f3));
    }

    f4 acc[4][4];
    const f4 zero4 = { 0.f, 0.f, 0.f, 0.f };

    // layer 0: 4 -> 64
    {
        f16x8 a0[4];
#pragma unroll
        for (int mt = 0; mt < 4; ++mt)
            a0[mt] = *(const f16x8*)&wp[UA0 + (mt * 64 + lane) * 8];
#pragma unroll
        for (int nt = 0; nt < 4; ++nt) {
            int src = nt * 16 + ln;
            unsigned h01 = (unsigned)__shfl((int)FH01, src);
            unsigned h23 = (unsigned)__shfl((int)FH23, src);
            unsigned l01 = (unsigned)__shfl((int)FL01, src);
            unsigned l23 = (unsigned)__shfl((int)FL23, src);
            u4 bu;
            bu[0] = (q == 0) ? h01 : ((q == 1) ? l01 : 0u);
            bu[1] = (q == 0) ? h23 : ((q == 1) ? l23 : 0u);
            bu[2] = (q == 0) ? h01 : 0u;
            bu[3] = (q == 0) ? h23 : 0u;
            f16x8 bf = __builtin_bit_cast(f16x8, bu);
#pragma unroll
            for (int mt = 0; mt < 4; ++mt)
                acc[mt][nt] = __builtin_amdgcn_mfma_f32_16x16x32_f16(a0[mt], bf, zero4, 0, 0, 0);
        }
    }

    u4 Bu[4][2];
    epi_frag(acc, b0g, q, Bu);
    mid_layer(acc, wp + UA1H, wp + UA1L, lane, Bu);
    epi_frag(acc, b1g, q, Bu);
    mid_layer(acc, wp + UA2H, wp + UA2L, lane, Bu);
    epi_frag(acc, b2g, q, Bu);

    // layer 3: 64 -> 8, coalesced row-segment write only
    {
        f16x8 a3h0 = *(const f16x8*)&wp[UA3H + (0 * 64 + lane) * 8];
        f16x8 a3h1 = *(const f16x8*)&wp[UA3H + (1 * 64 + lane) * 8];
        f16x8 a3l0 = *(const f16x8*)&wp[UA3L + (0 * 64 + lane) * 8];
        f16x8 a3l1 = *(const f16x8*)&wp[UA3L + (1 * 64 + lane) * 8];
        f4 acc3[4];
#pragma unroll
        for (int nt = 0; nt < 4; ++nt) {
            f16x8 b0 = __builtin_bit_cast(f16x8, Bu[nt][0]);
            f16x8 b1 = __builtin_bit_cast(f16x8, Bu[nt][1]);
            f4 c = zero4;
            c = __builtin_amdgcn_mfma_f32_16x16x32_f16(a3h0, b0, c, 0, 0, 0);
            c = __builtin_amdgcn_mfma_f32_16x16x32_f16(a3l0, b0, c, 0, 0, 0);
            c = __builtin_amdgcn_mfma_f32_16x16x32_f16(a3h1, b1, c, 0, 0, 0);
            c = __builtin_amdgcn_mfma_f32_16x16x32_f16(a3l1, b1, c, 0, 0, 0);
            acc3[nt] = c;
        }
        if (q < 2) {
            f4 b3v = *(const f4*)&b3g[q * 4];
#pragma unroll
            for (int nt = 0; nt < 4; ++nt) {
                int jc = j0 + nt * 16 + ln;
#pragma unroll
                for (int r = 0; r < 4; ++r) {
                    int out = q * 4 + r;
                    bias_out[(((size_t)(b * H_ + out)) * N_ + i) * N_ + jc] = acc3[nt][r] + b3v[r];
                }
            }
        }
    }
}

// ---------------- K_C: attention (MFMA flash-row, head-major f16 QKV) ----------------
#define SVT 264   // f16 stride of transposed V in LDS (264 = 4 mod 32 banks -> 2-way only)
__global__ __launch_bounds__(256) void k_attn(
    const float* __restrict__ ws,
    const _Float16* __restrict__ qh, const _Float16* __restrict__ kh,
    const _Float16* __restrict__ kl, const _Float16* __restrict__ vh,
    float* __restrict__ wso) {
    __shared__ __align__(16) _Float16 Vt[16 * SVT];
    int tid = threadIdx.x;
    int blk = blockIdx.x;                 // (b*8+h)*4 + ib
    int ib = blk & 3;
    int bh = blk >> 2;
    int b = bh >> 3;

    // stage V transposed: Vt[d][j] f16 (head-major -> contiguous 32B/lane read)
    {
        const _Float16* vr = vh + ((size_t)(bh * 256) + tid) * 16;
        f16x8 v0 = *(const f16x8*)vr;
        f16x8 v1 = *(const f16x8*)(vr + 8);
#pragma unroll
        for (int d = 0; d < 8; ++d) {
            Vt[d * SVT + tid] = v0[d];
            Vt[(8 + d) * SVT + tid] = v1[d];
        }
    }
    __syncthreads();

    int lane = tid & 63, w = tid >> 6;
    int ln = lane & 15, q = lane >> 4;
    int i0 = ib * 64 + w * 16;
    const f4 zero4 = { 0.f, 0.f, 0.f, 0.f };

    // B_Q: [Qh | Qh] across K=32 slots (d-half selected by q&1)
    f16x8 Bq = *(const f16x8*)&qh[((size_t)(bh * 256) + i0 + ln) * 16 + (q & 1) * 8];

    // S^T = K · Q^T : A = [K_hi (q<2) | K_lo (q>=2)], 16 m-tiles over j
    f4 accs[16];
    const _Float16* kbase = (q < 2 ? kh : kl) + ((size_t)(bh * 256)) * 16 + (q & 1) * 8;
    const float* bb = ws + OFF_BIAS + ((size_t)(bh * 256 + i0 + ln)) * 256 + q * 4;
    const float* tbb = ws + OFF_BIAS + ((size_t)bh) * 65536 + (i0 + ln);
#pragma unroll
    for (int mt = 0; mt < 16; ++mt) {
        f16x8 Ak = *(const f16x8*)&kbase[(size_t)(mt * 16 + ln) * 16];
        f4 s = __builtin_amdgcn_mfma_f32_16x16x32_f16(Ak, Bq, zero4, 0, 0, 0);
        f4 bias4;
        if ((mt >> 2) < ib) {
            // lower-triangle tile: read transposed (bias[j][i]); lanes span one 64B line per row
            const float* tb = tbb + (size_t)(mt * 16 + q * 4) * 256;
            bias4[0] = tb[0];
            bias4[1] = tb[256];
            bias4[2] = tb[512];
            bias4[3] = tb[768];
        } else {
            bias4 = *(const f4*)&bb[mt * 16];
        }
#pragma unroll
        for (int r = 0; r < 4; ++r) s[r] = fmaf(s[r], 0.25f, bias4[r]);
        accs[mt] = s;
    }

    // softmax over j (64 in-lane values + cross-q reduce; i = ln fixed per lane)
    float mx = accs[0][0];
#pragma unroll
    for (int mt = 0; mt < 16; ++mt)
#pragma unroll
        for (int r = 0; r < 4; ++r) mx = fmaxf(mx, accs[mt][r]);
    mx = fmaxf(mx, __shfl_xor(mx, 16));
    mx = fmaxf(mx, __shfl_xor(mx, 32));
    float nms = -mx * L2E_F;
    float l = 0.0f;
#pragma unroll
    for (int mt = 0; mt < 16; ++mt) {
#pragma unroll
        for (int r = 0; r < 4; ++r) {
            float p = __builtin_amdgcn_exp2f(fmaf(accs[mt][r], L2E_F, nms));
            accs[mt][r] = p;
            l += p;
        }
    }
    l += __shfl_xor(l, 16);
    l += __shfl_xor(l, 32);
    float inv = __builtin_amdgcn_rcpf(l);

    // O^T = V^T_perm · P^T  (kappa: in-lane P pack, permuted V read)
    f4 o = zero4;
#pragma unroll
    for (int ks = 0; ks < 8; ++ks) {
        u4 bp = { pkh2(accs[2 * ks][0], accs[2 * ks][1]),
                  pkh2(accs[2 * ks][2], accs[2 * ks][3]),
                  pkh2(accs[2 * ks + 1][0], accs[2 * ks + 1][1]),
                  pkh2(accs[2 * ks + 1][2], accs[2 * ks + 1][3]) };
        int vb = ln * SVT + 32 * ks + 4 * q;
        f16x4 lo4 = *(const f16x4*)&Vt[vb];
        f16x4 hi4 = *(const f16x4*)&Vt[vb + 16];
        f16x8 av;
        av[0] = lo4[0]; av[1] = lo4[1]; av[2] = lo4[2]; av[3] = lo4[3];
        av[4] = hi4[0]; av[5] = hi4[1]; av[6] = hi4[2]; av[7] = hi4[3];
        o = __builtin_amdgcn_mfma_f32_16x16x32_f16(av, __builtin_bit_cast(f16x8, bp), o, 0, 0, 0);
    }
    f4 res = o * inv;
    int h = bh & 7;
    *(f4*)(wso + OFF_AO + ((size_t)(b * 256 + i0 + ln)) * 128 + h * 16 + q * 4) = res;
}

// ---------------- K_D: output projection (MFMA) — 128 blocks x 4 waves ----------------
__global__ __launch_bounds__(256) void k_out(
    const float* __restrict__ ws, const _Float16* __restrict__ wp,
    const float* __restrict__ bo, float* __restrict__ out) {
    int tid = threadIdx.x;
    int lane = tid & 63, ln = lane & 15, q = lane >> 4;
    int wid = blockIdx.x * 4 + (tid >> 6);       // 0..511
    int og = wid & 1, tg = wid >> 1;
    const _Float16* wpm = wp + UQKV + 3 * 32768;
    size_t tok = (size_t)(tg * 16 + ln);
    f4 cc[4];
    mfma_core64x16(ws + OFF_AO + tok * 128, wpm, og * 4, bo + og * 64, lane, cc);
#pragma unroll
    for (int mtl = 0; mtl < 4; ++mtl)
        *(f4*)(out + tok * 128 + og * 64 + mtl * 16 + q * 4) = cc[mtl];
}

extern "C" void kernel_launch(void* const* d_in, const int* in_sizes, int n_in,
                              void* d_out, int out_size, void* d_ws, size_t ws_size,
                              hipStream_t stream) {
    const float* x_pf   = (const float*)d_in[0];
    const float* x_feat = (const float*)d_in[1];
    const float* w0 = (const float*)d_in[2];
    const float* b0 = (const float*)d_in[3];
    const float* w1 = (const float*)d_in[4];
    const float* b1 = (const float*)d_in[5];
    const float* w2 = (const float*)d_in[6];
    const float* b2 = (const float*)d_in[7];
    const float* w3 = (const float*)d_in[8];
    const float* b3 = (const float*)d_in[9];
    const float* wq = (const float*)d_in[10];
    const float* wk = (const float*)d_in[11];
    const float* wv = (const float*)d_in[12];
    const float* wo = (const float*)d_in[13];
    const float* bq = (const float*)d_in[14];
    const float* bk = (const float*)d_in[15];
    const float* bv = (const float*)d_in[16];
    const float* bo = (const float*)d_in[17];
    float* ws  = (float*)d_ws;
    float* out = (float*)d_out;
    _Float16* wpack = (_Float16*)(ws + OFF_WPACK);
    _Float16* qh = (_Float16*)(ws + OFF_Q);
    _Float16* kh = qh + 524288;
    _Float16* kl = kh + 524288;
    _Float16* vh = kl + 524288;

    hipLaunchKernelGGL(k_prep, dim3(80), dim3(256), 0, stream,
                       w0, w1, w2, w3, wq, wk, wv, wo, x_pf, wpack, ws);
    hipLaunchKernelGGL(k_pair_qkv, dim3(384 + 2560), dim3(256), 0, stream,
                       ws, wpack, b0, b1, b2, b3, ws + OFF_BIAS,
                       x_feat, bq, bk, bv, qh, kh, kl, vh);
    hipLaunchKernelGGL(k_attn, dim3(512), dim3(256), 0, stream, ws, qh, kh, kl, vh, ws);
    hipLaunchKernelGGL(k_out, dim3(128), dim3(256), 0, stream, ws, wpack, bo, out);
}

// Round 10
// 157.741 us; speedup vs baseline: 1.6425x; 1.6425x over previous
//
#include <hip/hip_runtime.h>
#include <hip/hip_bf16.h>
#include <math.h>

#define B_ 16
#define N_ 256
#define D_ 128
#define H_ 8
#define HD_ 16
#define EPS_ 1e-8f
#define PI_F 3.14159265358979323846f
#define TWO_PI_F 6.28318530717958647692f
#define INV_TWO_PI_F 0.15915494309189533577f
#define L2E_F 1.4426950408889634f

// ---------------- workspace layout (float units) ----------------
#define OFF_PT   0               // 4096
#define OFF_RAP  4096
#define OFF_PHI  8192
#define OFF_PX   12288
#define OFF_PY   16384
#define OFF_PZ   20480
#define OFF_E    24576
#define OFF_Q    28672           // f16 region: QH/KH/KL/VH head-major, each 524288 f16
#define OFF_BIAS (28672 + 3*524288)     // 8388608 floats (B,H,N,N), upper-tri tiles only
#define OFF_AO   (OFF_BIAS + 8388608)   // 524288
#define OFF_WPACK (OFF_AO + 524288)     // packed f16 weight frags

// packed weight-frag offsets (f16 units, relative to wp)
#define UA0  0        // 2048 : layer0 combined hi/lo k-slot packing
#define UA1H 2048     // 4096
#define UA1L 6144     // 4096
#define UA2H 10240    // 4096
#define UA2L 14336    // 4096
#define UA3H 18432    // 1024
#define UA3L 19456    // 1024
#define UQKV 20480    // 4 matrices (wq,wk,wv,wo): each hi 16384 + lo 16384

typedef _Float16 f16x8 __attribute__((ext_vector_type(8)));
typedef _Float16 f16x4 __attribute__((ext_vector_type(4)));
typedef _Float16 f16x2 __attribute__((ext_vector_type(2)));
typedef __attribute__((ext_vector_type(4))) float f4;
typedef __attribute__((ext_vector_type(4))) unsigned int u4;

__device__ __forceinline__ unsigned pkh2(float a, float b) {
    f16x2 v = { (_Float16)a, (_Float16)b };          // RNE conversions
    return __builtin_bit_cast(unsigned, v);
}
__device__ __forceinline__ float f16res(float x) {   // exact residual of RNE f16
    return x - (float)(_Float16)x;
}

__device__ __forceinline__ float gelu_f(float x) {
    // tanh-approx gelu == x * sigmoid(y); y*log2e = 2.3022079x + 0.10294337x^3
    float y2 = x * fmaf(0.10294337f, x * x, 2.3022079f);
    float e = __builtin_amdgcn_exp2f(-y2);           // inf-safe both tails
    return x * __builtin_amdgcn_rcpf(1.0f + e);
}

// kappa permutation: k-slot (ks,q,j) <-> original index (2*(j>>2)+ks)*16 + q*4 + (j&3)

// ---------------- K_A: weight packing (blocks 0-63) + particle features (64-79) -------------
__global__ __launch_bounds__(256) void k_prep(
    const float* __restrict__ w0, const float* __restrict__ w1,
    const float* __restrict__ w2, const float* __restrict__ w3,
    const float* __restrict__ wq, const float* __restrict__ wk,
    const float* __restrict__ wv, const float* __restrict__ wo,
    const float* __restrict__ x_pf,
    _Float16* __restrict__ wp, float* __restrict__ ws) {
    if (blockIdx.x >= 64) {
        int idx = (blockIdx.x - 64) * 256 + threadIdx.x;   // 0..4095
        int b = idx >> 8, n = idx & 255;
        const float* base = x_pf + (size_t)b * 4 * N_;
        float px = base[0 * N_ + n];
        float py = base[1 * N_ + n];
        float pz = base[2 * N_ + n];
        float e  = base[3 * N_ + n];
        float pt  = sqrtf(fmaxf(px * px + py * py, EPS_));
        float rap = 0.5f * log1pf(2.0f * pz / fmaxf(e - pz, 1e-20f));
        float phi = atan2f(py, px);
        ws[OFF_PT  + idx] = pt;
        ws[OFF_RAP + idx] = rap;
        ws[OFF_PHI + idx] = phi;
        ws[OFF_PX  + idx] = px;
        ws[OFF_PY  + idx] = py;
        ws[OFF_PZ  + idx] = pz;
        ws[OFF_E   + idx] = e;
        return;
    }
    int id0 = blockIdx.x * 256 + threadIdx.x;
    const int gs = 64 * 256;
    for (int e = id0; e < 2048; e += gs) {
        int fi = e >> 3, j = e & 7;
        int mt = fi >> 6, lane = fi & 63;
        int q = lane >> 4, ln = lane & 15;
        int m = mt * 16 + ln;
        _Float16 v = (_Float16)0.0f;
        if (q == 0) v = (j < 4) ? (_Float16)w0[j * 64 + m]
                                : (_Float16)f16res(w0[(j - 4) * 64 + m]);
        else if (q == 1) v = (j < 4) ? (_Float16)w0[j * 64 + m] : (_Float16)0.0f;
        wp[UA0 + e] = v;
    }
    for (int e = id0; e < 4096; e += gs) {
        int fi = e >> 3, j = e & 7;
        int mt = fi >> 7, ks = (fi >> 6) & 1, lane = fi & 63;
        int q = lane >> 4;
        int m = mt * 16 + (lane & 15);
        int k = (2 * (j >> 2) + ks) * 16 + q * 4 + (j & 3);   // kappa
        float x1 = w1[k * 64 + m];
        wp[UA1H + e] = (_Float16)x1;
        wp[UA1L + e] = (_Float16)f16res(x1);
        float x2 = w2[k * 64 + m];
        wp[UA2H + e] = (_Float16)x2;
        wp[UA2L + e] = (_Float16)f16res(x2);
    }
    for (int e = id0; e < 1024; e += gs) {
        int fi = e >> 3, j = e & 7;
        int ks = fi >> 6, lane = fi & 63;
        int q = lane >> 4;
        int m = lane & 15;
        int k = (2 * (j >> 2) + ks) * 16 + q * 4 + (j & 3);   // kappa
        float x = (m < 8) ? w3[k * 8 + m] : 0.0f;
        wp[UA3H + e] = (_Float16)x;
        wp[UA3L + e] = (_Float16)f16res(x);
    }
    const float* mats[4] = { wq, wk, wv, wo };
#pragma unroll 1
    for (int mi = 0; mi < 4; ++mi) {
        const float* W = mats[mi];
        _Float16* dst = wp + UQKV + mi * 32768;
        for (int e = id0; e < 16384; e += gs) {
            int fi = e >> 3, j = e & 7;
            int mt = fi >> 8, ks = (fi >> 6) & 3, lane = fi & 63;
            int k = ks * 32 + ((lane >> 4) << 3) + j;
            int o = mt * 16 + (lane & 15);
            float x = W[k * 128 + o];
            dst[e] = (_Float16)x;
            dst[16384 + e] = (_Float16)f16res(x);
        }
    }
}

// epilogue: bias + gelu on C-layout accs, pack straight into next-layer B-frags (in-lane).
__device__ __forceinline__ void epi_frag(const f4 (&acc)[4][4], const float* __restrict__ bg,
                                         int q, u4 (&Bu)[4][2]) {
#pragma unroll
    for (int mt = 0; mt < 4; ++mt) {
        f4 bv = *(const f4*)&bg[mt * 16 + q * 4];
        int ks = mt & 1, hi = (mt >> 1) * 2;
#pragma unroll
        for (int nt = 0; nt < 4; ++nt) {
            float g0 = gelu_f(acc[mt][nt][0] + bv[0]);
            float g1 = gelu_f(acc[mt][nt][1] + bv[1]);
            float g2 = gelu_f(acc[mt][nt][2] + bv[2]);
            float g3 = gelu_f(acc[mt][nt][3] + bv[3]);
            Bu[nt][ks][hi]     = pkh2(g0, g1);
            Bu[nt][ks][hi + 1] = pkh2(g2, g3);
        }
    }
}

__device__ __forceinline__ void mid_layer(f4 (&acc)[4][4],
                                          const _Float16* __restrict__ wh,
                                          const _Float16* __restrict__ wl,
                                          int lane, const u4 (&Bu)[4][2]) {
    const f4 zero4 = { 0.f, 0.f, 0.f, 0.f };
#pragma unroll
    for (int mt = 0; mt < 4; ++mt) {
        f16x8 ah0 = *(const f16x8*)&wh[((mt * 2 + 0) * 64 + lane) * 8];
        f16x8 ah1 = *(const f16x8*)&wh[((mt * 2 + 1) * 64 + lane) * 8];
        f16x8 al0 = *(const f16x8*)&wl[((mt * 2 + 0) * 64 + lane) * 8];
        f16x8 al1 = *(const f16x8*)&wl[((mt * 2 + 1) * 64 + lane) * 8];
#pragma unroll
        for (int nt = 0; nt < 4; ++nt) {
            f16x8 b0 = __builtin_bit_cast(f16x8, Bu[nt][0]);
            f16x8 b1 = __builtin_bit_cast(f16x8, Bu[nt][1]);
            f4 c = zero4;
            c = __builtin_amdgcn_mfma_f32_16x16x32_f16(ah0, b0, c, 0, 0, 0);
            c = __builtin_amdgcn_mfma_f32_16x16x32_f16(al0, b0, c, 0, 0, 0);
            c = __builtin_amdgcn_mfma_f32_16x16x32_f16(ah1, b1, c, 0, 0, 0);
            c = __builtin_amdgcn_mfma_f32_16x16x32_f16(al1, b1, c, 0, 0, 0);
            acc[mt][nt] = c;
        }
    }
}

// ---------------- split-f16 64-out x 16-token MFMA core ----------------
__device__ __forceinline__ void mfma_core64x16(
    const float* __restrict__ xrow, const _Float16* __restrict__ wpm,
    int mtbase, const float* __restrict__ biasv, int lane, f4 (&cc)[4]) {
    int q = lane >> 4;
    const f4 zero4 = { 0.f, 0.f, 0.f, 0.f };
    f16x8 Bh[4], Bl[4];
#pragma unroll
    for (int ks = 0; ks < 4; ++ks) {
        const float* p = xrow + ks * 32 + q * 8;
        float4 xa = ((const float4*)p)[0];
        float4 xb = ((const float4*)p)[1];
        u4 hu = { pkh2(xa.x, xa.y), pkh2(xa.z, xa.w), pkh2(xb.x, xb.y), pkh2(xb.z, xb.w) };
        u4 lu = { pkh2(f16res(xa.x), f16res(xa.y)), pkh2(f16res(xa.z), f16res(xa.w)),
                  pkh2(f16res(xb.x), f16res(xb.y)), pkh2(f16res(xb.z), f16res(xb.w)) };
        Bh[ks] = __builtin_bit_cast(f16x8, hu);
        Bl[ks] = __builtin_bit_cast(f16x8, lu);
    }
#pragma unroll
    for (int mtl = 0; mtl < 4; ++mtl) {
        int mt = mtbase + mtl;
        f4 c = zero4;
#pragma unroll
        for (int ks = 0; ks < 4; ++ks) {
            const _Float16* fa = wpm + ((size_t)((mt * 4 + ks) * 64 + lane)) * 8;
            f16x8 ah = *(const f16x8*)fa;
            f16x8 al = *(const f16x8*)(fa + 16384);
            c = __builtin_amdgcn_mfma_f32_16x16x32_f16(ah, Bh[ks], c, 0, 0, 0);
            c = __builtin_amdgcn_mfma_f32_16x16x32_f16(ah, Bl[ks], c, 0, 0, 0);
            c = __builtin_amdgcn_mfma_f32_16x16x32_f16(al, Bh[ks], c, 0, 0, 0);
        }
        f4 bv = *(const f4*)&biasv[mtl * 16 + q * 4];
        cc[mtl] = c + bv;
    }
}

// ---------------- K_B: QKV (blocks 0-383) + symmetric pair MLP (blocks 384+) ----------
// Q/K/V outputs stored HEAD-MAJOR: [b][h][tok][16] f16 -> fully coalesced attn loads.
// NOTE: __launch_bounds__(256,4) — (256,8) capped unified VGPR/AGPR at 64 and spilled
// the whole working set to scratch (round 9: FETCH 206MB/WRITE 445MB, 2.7x regression).
__global__ __launch_bounds__(256, 4) void k_pair_qkv(
    const float* __restrict__ ws, const _Float16* __restrict__ wp,
    const float* __restrict__ b0g, const float* __restrict__ b1g,
    const float* __restrict__ b2g, const float* __restrict__ b3g,
    float* __restrict__ bias_out,
    const float* __restrict__ xf,
    const float* __restrict__ bqv, const float* __restrict__ bkv, const float* __restrict__ bvv,
    _Float16* __restrict__ qh, _Float16* __restrict__ kh,
    _Float16* __restrict__ kl, _Float16* __restrict__ vh) {
    int tid = threadIdx.x;
    int lane = tid & 63;
    int ln = lane & 15, q = lane >> 4;

    if (blockIdx.x < 384) {
        // -------- QKV projection -> head-major packed f16 outputs --------
        int wid = blockIdx.x * 4 + (tid >> 6);       // 0..1535
        int og = wid % 6, tg = wid / 6;
        int mi = og >> 1, ch = og & 1;
        const _Float16* wpm = wp + UQKV + mi * 32768;
        const float* bias = (mi == 0) ? bqv : ((mi == 1) ? bkv : bvv);
        size_t tok = (size_t)(tg * 16 + ln);
        f4 cc[4];
        mfma_core64x16(xf + tok * 128, wpm, ch * 4, bias + ch * 64, lane, cc);
        _Float16* hout = (mi == 0) ? qh : ((mi == 1) ? kh : vh);
        int b = (int)(tok >> 8), tl = (int)(tok & 255);
#pragma unroll
        for (int mtl = 0; mtl < 4; ++mtl) {
            int head = ch * 4 + mtl;
            size_t off = ((size_t)((b * 8 + head) * 256 + tl)) * 16 + q * 4;
            f16x4 hv;
#pragma unroll
            for (int r = 0; r < 4; ++r) hv[r] = (_Float16)cc[mtl][r];
            *(f16x4*)&hout[off] = hv;
            if (mi == 1) {
                f16x4 lv;
#pragma unroll
                for (int r = 0; r < 4; ++r) lv[r] = (_Float16)(cc[mtl][r] - (float)hv[r]);
                *(f16x4*)&kl[off] = lv;
            }
        }
        return;
    }

    // -------- pair MLP (upper-triangle wave-tiles; no mirror writes) --------
    int w2 = (blockIdx.x - 384) * 4 + (tid >> 6);    // 0..10239
    int b = w2 / 640;
    int w = w2 - b * 640;
    int it, rr, nj;
    if (w < 256)      { it = 0; rr = w;       nj = 4; }
    else if (w < 448) { it = 1; rr = w - 256; nj = 3; }
    else if (w < 576) { it = 2; rr = w - 448; nj = 2; }
    else              { it = 3; rr = w - 576; nj = 1; }
    int i  = it * 64 + rr / nj;
    int jt = it + rr % nj;
    int j0 = jt * 64;
    int row = (b << 8) + i;

    unsigned FH01, FH23, FL01, FL23;
    {
        int ib = row;
        int jb = (b << 8) + j0 + lane;
        float pt_i = ws[OFF_PT + ib],  rap_i = ws[OFF_RAP + ib], phi_i = ws[OFF_PHI + ib];
        float px_i = ws[OFF_PX + ib],  py_i  = ws[OFF_PY  + ib];
        float pz_i = ws[OFF_PZ + ib],  e_i   = ws[OFF_E   + ib];
        float pt_j = ws[OFF_PT + jb],  rap_j = ws[OFF_RAP + jb], phi_j = ws[OFF_PHI + jb];
        float px_j = ws[OFF_PX + jb],  py_j  = ws[OFF_PY  + jb];
        float pz_j = ws[OFF_PZ + jb],  e_j   = ws[OFF_E   + jb];

        float drap = rap_i - rap_j;
        float xw = phi_i - phi_j + PI_F;
        float mw = xw - TWO_PI_F * floorf(xw * INV_TWO_PI_F);
        float dphi = mw - PI_F;
        float delta = sqrtf(drap * drap + dphi * dphi);
        float f2 = __logf(fmaxf(delta, EPS_));
        float ptmin = fminf(pt_i, pt_j);
        float f0 = __logf(fmaxf(ptmin * delta, EPS_));
        float f1 = __logf(fmaxf(ptmin / fmaxf(pt_i + pt_j, EPS_), EPS_));
        float es = e_i + e_j, pxs = px_i + px_j, pys = py_i + py_j, pzs = pz_i + pz_j;
        float f3 = __logf(fmaxf(es * es - pxs * pxs - pys * pys - pzs * pzs, EPS_));

        FH01 = pkh2(f0, f1);
        FH23 = pkh2(f2, f3);
        FL01 = pkh2(f16res(f0), f16res(f1));
        FL23 = pkh2(f16res(f2), f16res(f3));
    }

    f4 acc[4][4];
    const f4 zero4 = { 0.f, 0.f, 0.f, 0.f };

    // layer 0: 4 -> 64
    {
        f16x8 a0[4];
#pragma unroll
        for (int mt = 0; mt < 4; ++mt)
            a0[mt] = *(const f16x8*)&wp[UA0 + (mt * 64 + lane) * 8];
#pragma unroll
        for (int nt = 0; nt < 4; ++nt) {
            int src = nt * 16 + ln;
            unsigned h01 = (unsigned)__shfl((int)FH01, src);
            unsigned h23 = (unsigned)__shfl((int)FH23, src);
            unsigned l01 = (unsigned)__shfl((int)FL01, src);
            unsigned l23 = (unsigned)__shfl((int)FL23, src);
            u4 bu;
            bu[0] = (q == 0) ? h01 : ((q == 1) ? l01 : 0u);
            bu[1] = (q == 0) ? h23 : ((q == 1) ? l23 : 0u);
            bu[2] = (q == 0) ? h01 : 0u;
            bu[3] = (q == 0) ? h23 : 0u;
            f16x8 bf = __builtin_bit_cast(f16x8, bu);
#pragma unroll
            for (int mt = 0; mt < 4; ++mt)
                acc[mt][nt] = __builtin_amdgcn_mfma_f32_16x16x32_f16(a0[mt], bf, zero4, 0, 0, 0);
        }
    }

    u4 Bu[4][2];
    epi_frag(acc, b0g, q, Bu);
    mid_layer(acc, wp + UA1H, wp + UA1L, lane, Bu);
    epi_frag(acc, b1g, q, Bu);
    mid_layer(acc, wp + UA2H, wp + UA2L, lane, Bu);
    epi_frag(acc, b2g, q, Bu);

    // layer 3: 64 -> 8, coalesced row-segment write only
    {
        f16x8 a3h0 = *(const f16x8*)&wp[UA3H + (0 * 64 + lane) * 8];
        f16x8 a3h1 = *(const f16x8*)&wp[UA3H + (1 * 64 + lane) * 8];
        f16x8 a3l0 = *(const f16x8*)&wp[UA3L + (0 * 64 + lane) * 8];
        f16x8 a3l1 = *(const f16x8*)&wp[UA3L + (1 * 64 + lane) * 8];
        f4 acc3[4];
#pragma unroll
        for (int nt = 0; nt < 4; ++nt) {
            f16x8 b0 = __builtin_bit_cast(f16x8, Bu[nt][0]);
            f16x8 b1 = __builtin_bit_cast(f16x8, Bu[nt][1]);
            f4 c = zero4;
            c = __builtin_amdgcn_mfma_f32_16x16x32_f16(a3h0, b0, c, 0, 0, 0);
            c = __builtin_amdgcn_mfma_f32_16x16x32_f16(a3l0, b0, c, 0, 0, 0);
            c = __builtin_amdgcn_mfma_f32_16x16x32_f16(a3h1, b1, c, 0, 0, 0);
            c = __builtin_amdgcn_mfma_f32_16x16x32_f16(a3l1, b1, c, 0, 0, 0);
            acc3[nt] = c;
        }
        if (q < 2) {
            f4 b3v = *(const f4*)&b3g[q * 4];
#pragma unroll
            for (int nt = 0; nt < 4; ++nt) {
                int jc = j0 + nt * 16 + ln;
#pragma unroll
                for (int r = 0; r < 4; ++r) {
                    int out = q * 4 + r;
                    bias_out[(((size_t)(b * H_ + out)) * N_ + i) * N_ + jc] = acc3[nt][r] + b3v[r];
                }
            }
        }
    }
}

// ---------------- K_C: attention (MFMA flash-row, head-major f16 QKV) ----------------
#define SVT 264   // f16 stride of transposed V in LDS (264 = 4 mod 32 banks -> 2-way only)
__global__ __launch_bounds__(256) void k_attn(
    const float* __restrict__ ws,
    const _Float16* __restrict__ qh, const _Float16* __restrict__ kh,
    const _Float16* __restrict__ kl, const _Float16* __restrict__ vh,
    float* __restrict__ wso) {
    __shared__ __align__(16) _Float16 Vt[16 * SVT];
    int tid = threadIdx.x;
    int blk = blockIdx.x;                 // (b*8+h)*4 + ib
    int ib = blk & 3;
    int bh = blk >> 2;
    int b = bh >> 3;

    // stage V transposed: Vt[d][j] f16 (head-major -> contiguous 32B/lane read)
    {
        const _Float16* vr = vh + ((size_t)(bh * 256) + tid) * 16;
        f16x8 v0 = *(const f16x8*)vr;
        f16x8 v1 = *(const f16x8*)(vr + 8);
#pragma unroll
        for (int d = 0; d < 8; ++d) {
            Vt[d * SVT + tid] = v0[d];
            Vt[(8 + d) * SVT + tid] = v1[d];
        }
    }
    __syncthreads();

    int lane = tid & 63, w = tid >> 6;
    int ln = lane & 15, q = lane >> 4;
    int i0 = ib * 64 + w * 16;
    const f4 zero4 = { 0.f, 0.f, 0.f, 0.f };

    // B_Q: [Qh | Qh] across K=32 slots (d-half selected by q&1)
    f16x8 Bq = *(const f16x8*)&qh[((size_t)(bh * 256) + i0 + ln) * 16 + (q & 1) * 8];

    // S^T = K · Q^T : A = [K_hi (q<2) | K_lo (q>=2)], 16 m-tiles over j
    f4 accs[16];
    const _Float16* kbase = (q < 2 ? kh : kl) + ((size_t)(bh * 256)) * 16 + (q & 1) * 8;
    const float* bb = ws + OFF_BIAS + ((size_t)(bh * 256 + i0 + ln)) * 256 + q * 4;
    const float* tbb = ws + OFF_BIAS + ((size_t)bh) * 65536 + (i0 + ln);
#pragma unroll
    for (int mt = 0; mt < 16; ++mt) {
        f16x8 Ak = *(const f16x8*)&kbase[(size_t)(mt * 16 + ln) * 16];
        f4 s = __builtin_amdgcn_mfma_f32_16x16x32_f16(Ak, Bq, zero4, 0, 0, 0);
        f4 bias4;
        if ((mt >> 2) < ib) {
            // lower-triangle tile: read transposed (bias[j][i]); lanes span one 64B line per row
            const float* tb = tbb + (size_t)(mt * 16 + q * 4) * 256;
            bias4[0] = tb[0];
            bias4[1] = tb[256];
            bias4[2] = tb[512];
            bias4[3] = tb[768];
        } else {
            bias4 = *(const f4*)&bb[mt * 16];
        }
#pragma unroll
        for (int r = 0; r < 4; ++r) s[r] = fmaf(s[r], 0.25f, bias4[r]);
        accs[mt] = s;
    }

    // softmax over j (64 in-lane values + cross-q reduce; i = ln fixed per lane)
    float mx = accs[0][0];
#pragma unroll
    for (int mt = 0; mt < 16; ++mt)
#pragma unroll
        for (int r = 0; r < 4; ++r) mx = fmaxf(mx, accs[mt][r]);
    mx = fmaxf(mx, __shfl_xor(mx, 16));
    mx = fmaxf(mx, __shfl_xor(mx, 32));
    float nms = -mx * L2E_F;
    float l = 0.0f;
#pragma unroll
    for (int mt = 0; mt < 16; ++mt) {
#pragma unroll
        for (int r = 0; r < 4; ++r) {
            float p = __builtin_amdgcn_exp2f(fmaf(accs[mt][r], L2E_F, nms));
            accs[mt][r] = p;
            l += p;
        }
    }
    l += __shfl_xor(l, 16);
    l += __shfl_xor(l, 32);
    float inv = __builtin_amdgcn_rcpf(l);

    // O^T = V^T_perm · P^T  (kappa: in-lane P pack, permuted V read)
    f4 o = zero4;
#pragma unroll
    for (int ks = 0; ks < 8; ++ks) {
        u4 bp = { pkh2(accs[2 * ks][0], accs[2 * ks][1]),
                  pkh2(accs[2 * ks][2], accs[2 * ks][3]),
                  pkh2(accs[2 * ks + 1][0], accs[2 * ks + 1][1]),
                  pkh2(accs[2 * ks + 1][2], accs[2 * ks + 1][3]) };
        int vb = ln * SVT + 32 * ks + 4 * q;
        f16x4 lo4 = *(const f16x4*)&Vt[vb];
        f16x4 hi4 = *(const f16x4*)&Vt[vb + 16];
        f16x8 av;
        av[0] = lo4[0]; av[1] = lo4[1]; av[2] = lo4[2]; av[3] = lo4[3];
        av[4] = hi4[0]; av[5] = hi4[1]; av[6] = hi4[2]; av[7] = hi4[3];
        o = __builtin_amdgcn_mfma_f32_16x16x32_f16(av, __builtin_bit_cast(f16x8, bp), o, 0, 0, 0);
    }
    f4 res = o * inv;
    int h = bh & 7;
    *(f4*)(wso + OFF_AO + ((size_t)(b * 256 + i0 + ln)) * 128 + h * 16 + q * 4) = res;
}

// ---------------- K_D: output projection (MFMA) — 128 blocks x 4 waves ----------------
__global__ __launch_bounds__(256) void k_out(
    const float* __restrict__ ws, const _Float16* __restrict__ wp,
    const float* __restrict__ bo, float* __restrict__ out) {
    int tid = threadIdx.x;
    int lane = tid & 63, ln = lane & 15, q = lane >> 4;
    int wid = blockIdx.x * 4 + (tid >> 6);       // 0..511
    int og = wid & 1, tg = wid >> 1;
    const _Float16* wpm = wp + UQKV + 3 * 32768;
    size_t tok = (size_t)(tg * 16 + ln);
    f4 cc[4];
    mfma_core64x16(ws + OFF_AO + tok * 128, wpm, og * 4, bo + og * 64, lane, cc);
#pragma unroll
    for (int mtl = 0; mtl < 4; ++mtl)
        *(f4*)(out + tok * 128 + og * 64 + mtl * 16 + q * 4) = cc[mtl];
}

extern "C" void kernel_launch(void* const* d_in, const int* in_sizes, int n_in,
                              void* d_out, int out_size, void* d_ws, size_t ws_size,
                              hipStream_t stream) {
    const float* x_pf   = (const float*)d_in[0];
    const float* x_feat = (const float*)d_in[1];
    const float* w0 = (const float*)d_in[2];
    const float* b0 = (const float*)d_in[3];
    const float* w1 = (const float*)d_in[4];
    const float* b1 = (const float*)d_in[5];
    const float* w2 = (const float*)d_in[6];
    const float* b2 = (const float*)d_in[7];
    const float* w3 = (const float*)d_in[8];
    const float* b3 = (const float*)d_in[9];
    const float* wq = (const float*)d_in[10];
    const float* wk = (const float*)d_in[11];
    const float* wv = (const float*)d_in[12];
    const float* wo = (const float*)d_in[13];
    const float* bq = (const float*)d_in[14];
    const float* bk = (const float*)d_in[15];
    const float* bv = (const float*)d_in[16];
    const float* bo = (const float*)d_in[17];
    float* ws  = (float*)d_ws;
    float* out = (float*)d_out;
    _Float16* wpack = (_Float16*)(ws + OFF_WPACK);
    _Float16* qh = (_Float16*)(ws + OFF_Q);
    _Float16* kh = qh + 524288;
    _Float16* kl = kh + 524288;
    _Float16* vh = kl + 524288;

    hipLaunchKernelGGL(k_prep, dim3(80), dim3(256), 0, stream,
                       w0, w1, w2, w3, wq, wk, wv, wo, x_pf, wpack, ws);
    hipLaunchKernelGGL(k_pair_qkv, dim3(384 + 2560), dim3(256), 0, stream,
                       ws, wpack, b0, b1, b2, b3, ws + OFF_BIAS,
                       x_feat, bq, bk, bv, qh, kh, kl, vh);
    hipLaunchKernelGGL(k_attn, dim3(512), dim3(256), 0, stream, ws, qh, kh, kl, vh, ws);
    hipLaunchKernelGGL(k_out, dim3(128), dim3(256), 0, stream, ws, wpack, bo, out);
}